// Round 1
// 831.178 us; speedup vs baseline: 1.2182x; 1.2182x over previous
//
#include <hip/hip_runtime.h>
#include <math.h>

// B=64, I=K=2048, H=N=2048, T=128.  m = b*128 + t (M=8192).
// Numerics contract (VALIDATED GREEN): Eigen gebp kc=320 K-panels; per C
// element an ascending-k FMA chain within each 320-panel (register
// accumulator), panels combined by UNFUSED f32 adds (beta=0 first).
// w_eff = __fmul_rn(weight, strength) rounded once. Scan: f32 state,
// unfused mul/add; exact batch mean via ballot/popcount; correctly-rounded
// expf via (float)exp((double)quotient).
//
// This round: GEMM staging rebuilt as async global_load_lds DMA into
// double-buffered LDS (T3 2-phase template), w*s hoisted to a precompute
// kernel so the B-operand is DMA-able. One barrier per k-tile; next tile's
// DMA issued before compute so the barrier's implicit vmcnt(0) drain is
// already satisfied. FMA chain order is bit-identical to the green kernel.

#define KT 32

__device__ __forceinline__ void async_copy16(const float* g, float* l) {
    __builtin_amdgcn_global_load_lds(
        (const __attribute__((address_space(1))) void*)g,
        (__attribute__((address_space(3))) void*)l, 16, 0, 0);
}

// weff[i][hl] = __fmul_rn(weight[i][h_base+hl], strength[i][h_base+hl])
// Chunk-local layout [2048][Hc] so GEMM B-rows are 128-col contiguous.
__global__ __launch_bounds__(256) void weff_kernel(
    const float* __restrict__ weight, const float* __restrict__ strength,
    float* __restrict__ weff, int h_base, int Hc)
{
    const int i = blockIdx.x;  // input row 0..2047
    const float* wr = weight   + (size_t)i * 2048 + h_base;
    const float* sr = strength + (size_t)i * 2048 + h_base;
    float* dr = weff + (size_t)i * Hc;
    for (int c = threadIdx.x * 4; c < Hc; c += 1024) {
        float4 wv = *(const float4*)&wr[c];
        float4 sv = *(const float4*)&sr[c];
        float4 o;
        o.x = __fmul_rn(wv.x, sv.x);
        o.y = __fmul_rn(wv.y, sv.y);
        o.z = __fmul_rn(wv.z, sv.z);
        o.w = __fmul_rn(wv.w, sv.w);
        *(float4*)&dr[c] = o;
    }
}

__global__ __launch_bounds__(256, 2) void gemm_kernel(
    const float* __restrict__ spikes,  // [B][I][T] = [64][2048][128]
    const float* __restrict__ weff,    // [I][Hc] chunk-local
    float* __restrict__ Ct,            // [Hc][M] chunk-local
    int Hc)
{
    // Linear (unpadded) tiles: required by global_load_lds (wave-uniform
    // dest + lane*16). Compute reads are conflict-free anyway: a-reads
    // broadcast (16 banks, 1 word each); b-reads are 2-way (free, m136).
    __shared__ __align__(16) float Ab[2][KT * 128];
    __shared__ __align__(16) float Wb[2][KT * 128];

    const int tid  = threadIdx.x;
    const int bx   = blockIdx.x;       // h-tile within chunk
    const int by   = blockIdx.y;       // batch b
    const int m0   = by * 128;
    const int h0l  = bx * 128;
    const int tx   = tid & 15;
    const int ty   = tid >> 4;
    const int widx = tid >> 6;         // wave 0..3
    const int lane = tid & 63;

    float acc[8][8];   // current 320-panel accumulator (ascending-k chain)
    float tot[8][8];   // running unfused panel total
#pragma unroll
    for (int i = 0; i < 8; i++)
#pragma unroll
        for (int j = 0; j < 8; j++) { acc[i][j] = 0.0f; tot[i][j] = 0.0f; }

    const float* a_base = spikes + (size_t)by * 262144;  // b * I * T

    // DMA-stage tile kt into buffer buf. Per wave: A gets 4 KiB (4 instrs,
    // tile is one contiguous 16 KiB global range), W gets 8 rows of 512 B
    // (4 instrs, 2 rows each: lanes 0-31 -> row r, lanes 32-63 -> row r+1).
    auto stage = [&](int buf, int kt) {
        const int k0 = kt * KT;
        const float* asrc = a_base + ((size_t)k0 << 7) + (widx << 10) + (lane << 2);
        float* adst = &Ab[buf][widx << 10];
#pragma unroll
        for (int i = 0; i < 4; i++)
            async_copy16(asrc + (i << 8), adst + (i << 8));

        const float* wsrc = weff + (size_t)(k0 + (widx << 3) + (lane >> 5)) * Hc
                            + h0l + ((lane & 31) << 2);
        float* wdst = &Wb[buf][widx << 10];
#pragma unroll
        for (int j = 0; j < 4; j++)
            async_copy16(wsrc + (size_t)(2 * j) * Hc, wdst + (j << 8));
    };

    stage(0, 0);
    __syncthreads();   // prologue drain (only exposed DMA latency)

    int cur = 0;
    for (int kt = 0; kt < 64; kt++) {
        if (kt < 63) stage(cur ^ 1, kt + 1);   // issue DMA, no wait

        // ascending-k FMA chain into the panel accumulator
#pragma unroll 4
        for (int k = 0; k < KT; k++) {
            float4 a0 = *(const float4*)&Ab[cur][(k << 7) + (ty << 2)];
            float4 a1 = *(const float4*)&Ab[cur][(k << 7) + (ty << 2) + 64];
            float4 b0 = *(const float4*)&Wb[cur][(k << 7) + (tx << 2)];
            float4 b1 = *(const float4*)&Wb[cur][(k << 7) + (tx << 2) + 64];
            float a[8] = {a0.x, a0.y, a0.z, a0.w, a1.x, a1.y, a1.z, a1.w};
            float b[8] = {b0.x, b0.y, b0.z, b0.w, b1.x, b1.y, b1.z, b1.w};
#pragma unroll
            for (int i = 0; i < 8; i++)
#pragma unroll
                for (int j = 0; j < 8; j++)
                    acc[i][j] = __builtin_fmaf(a[i], b[j], acc[i][j]);
        }

        // Eigen kc=320 panel boundary: unfused fold into total, reset chain
        if (((kt + 1) % 10 == 0) || (kt == 63)) {
#pragma unroll
            for (int i = 0; i < 8; i++)
#pragma unroll
                for (int j = 0; j < 8; j++) {
                    tot[i][j] = __fadd_rn(tot[i][j], acc[i][j]);
                    acc[i][j] = 0.0f;
                }
        }

        // Implicit vmcnt(0)+lgkmcnt(0) drain: next tile's DMA had the whole
        // compute phase to land, so this is cheap. Also fences buffer reuse.
        __syncthreads();
        cur ^= 1;
    }

#pragma unroll
    for (int j = 0; j < 8; j++) {
        const int hl = h0l + 4 * tx + (j & 3) + ((j >> 2) << 6);
        float4 v0 = make_float4(tot[0][j], tot[1][j], tot[2][j], tot[3][j]);
        float4 v1 = make_float4(tot[4][j], tot[5][j], tot[6][j], tot[7][j]);
        *(float4*)&Ct[(size_t)hl * 8192 + m0 + 4 * ty]      = v0;
        *(float4*)&Ct[(size_t)hl * 8192 + m0 + 4 * ty + 64] = v1;
    }
}

// One wave (64 lanes) per h; lane = batch b. Scan state f32, unfused.
// Batch-mean via ballot/popcount (exact). Validated numerics — UNCHANGED.
__global__ __launch_bounds__(256) void scan_kernel(
    const float* __restrict__ Wt,          // [Hc][B][T] f32 chunk-local
    const float* __restrict__ threshold,   // [H] f32 global
    const float* __restrict__ p_tau_mem,
    const float* __restrict__ p_tau_syn,
    const float* __restrict__ p_target,
    const float* __restrict__ p_lr,
    float* __restrict__ out,               // [B][H][T] f32 global
    int h_base)
{
    __shared__ float S[4 * 64 * 17];
    __shared__ unsigned int Bits[4][64][4];

    const int tid  = threadIdx.x;
    const int w    = tid >> 6;
    const int lane = tid & 63;            // batch b
    const int hl   = blockIdx.x * 4 + w;  // chunk-local h

    const float tau_mem = p_tau_mem[0];
    const float tau_syn = p_tau_syn[0];
    const float target  = p_target[0];
    const float lr      = p_lr[0];
    const float a_mem = (float)exp((double)__fdiv_rn(-0.001f, tau_mem));
    const float a_syn = (float)exp((double)__fdiv_rn(-0.001f, tau_syn));

    float i_syn = 0.0f, v_mem = 0.0f;
    float thr = threshold[h_base + hl];
    float fre = 0.0f;
    unsigned int bits[4] = {0u, 0u, 0u, 0u};

    const int st4 = tid & 3;
    const int sb  = (tid >> 2) & 63;

    for (int tc = 0; tc < 128; tc += 16) {
        __syncthreads();
#pragma unroll
        for (int hh = 0; hh < 4; hh++) {
            const int hg = blockIdx.x * 4 + hh;
            float4 v = *(const float4*)&Wt[(size_t)hg * 8192 + sb * 128 + tc + 4 * st4];
            float* row = &S[(hh * 64 + sb) * 17];
            row[4 * st4 + 0] = v.x;
            row[4 * st4 + 1] = v.y;
            row[4 * st4 + 2] = v.z;
            row[4 * st4 + 3] = v.w;
        }
        __syncthreads();

        const float* row = &S[(w * 64 + lane) * 17];
#pragma unroll
        for (int tt = 0; tt < 16; tt++) {
            const int t = tc + tt;
            const float wv = row[tt];
            i_syn = __fadd_rn(__fmul_rn(a_syn, i_syn), wv);
            v_mem = __fadd_rn(__fmul_rn(a_mem, v_mem), i_syn);
            const bool sp = (v_mem >= thr);
            const unsigned long long mask = __ballot(sp);
            if (sp) v_mem = __fsub_rn(v_mem, thr);
            const int cnt = __popcll(mask);
            const float rate = __fmul_rn((float)cnt, 0.015625f);
            fre = __fadd_rn(__fmul_rn(0.99f, fre), __fmul_rn(0.01f, rate));
            thr = __fadd_rn(thr, __fmul_rn(lr, __fsub_rn(fre, target)));
            if (sp) bits[t >> 5] |= (1u << (t & 31));
        }
    }

    __syncthreads();
    Bits[w][lane][0] = bits[0];
    Bits[w][lane][1] = bits[1];
    Bits[w][lane][2] = bits[2];
    Bits[w][lane][3] = bits[3];
    __syncthreads();

    for (int b = 0; b < 64; b++) {
        const unsigned int word = Bits[w][b][lane >> 4];
        float2 v;
        v.x = ((word >> ((2 * lane) & 31)) & 1u) ? 1.0f : 0.0f;
        v.y = ((word >> ((2 * lane + 1) & 31)) & 1u) ? 1.0f : 0.0f;
        *(float2*)&out[((size_t)b * 2048 + h_base + hl) * 128 + 2 * lane] = v;
    }
}

extern "C" void kernel_launch(void* const* d_in, const int* in_sizes, int n_in,
                              void* d_out, int out_size, void* d_ws, size_t ws_size,
                              hipStream_t stream) {
    const float* spikes    = (const float*)d_in[0];
    const float* weight    = (const float*)d_in[1];
    const float* strength  = (const float*)d_in[2];
    const float* threshold = (const float*)d_in[3];
    const float* tau_mem   = (const float*)d_in[4];
    const float* tau_syn   = (const float*)d_in[5];
    const float* target    = (const float*)d_in[6];
    const float* lr        = (const float*)d_in[7];

    float* out = (float*)d_out;

    // ws holds Wt [Hc][8192] f32 + weff [2048][Hc] f32 = Hc*40960 bytes.
    int Hc = 2048;
    while (Hc > 128 && (size_t)Hc * 40960ull > ws_size) Hc >>= 1;

    float* Wt   = (float*)d_ws;
    float* weff = (float*)d_ws + (size_t)Hc * 8192;

    for (int hb = 0; hb < 2048; hb += Hc) {
        weff_kernel<<<2048, 256, 0, stream>>>(weight, strength, weff, hb, Hc);
        gemm_kernel<<<dim3(Hc / 128, 64), 256, 0, stream>>>(spikes, weff, Wt, Hc);
        scan_kernel<<<Hc / 4, 256, 0, stream>>>(
            Wt, threshold, tau_mem, tau_syn, target, lr, out, hb);
    }
}